// Round 7
// baseline (8877.946 us; speedup 1.0000x reference)
//
#include <hip/hip_runtime.h>
#include <hip/hip_bf16.h>

#define NSAMP 8192
#define QL 5
#define MTOK (NSAMP*QL)   // 40960 tokens

typedef __hip_bfloat16 bf16;
typedef __attribute__((ext_vector_type(8))) __bf16 bf16x8;
typedef __attribute__((ext_vector_type(8))) unsigned short u16x8;
typedef __attribute__((ext_vector_type(4))) float f32x4;

__device__ __forceinline__ float bfu2f(unsigned short u){ return __uint_as_float(((unsigned)u)<<16); }
__device__ __forceinline__ float bf2f(bf16 v){ return __bfloat162float(v); }
__device__ __forceinline__ bf16  f2bf(float v){ return __float2bfloat16(v); }
__device__ __forceinline__ unsigned short f2bfu(float v){
  __hip_bfloat16 b = __float2bfloat16(v);
  return __builtin_bit_cast(unsigned short, b);
}

__device__ __forceinline__ void gload16(const void* g, void* l){
  __builtin_amdgcn_global_load_lds(
      (const __attribute__((address_space(1))) unsigned int*)g,
      (__attribute__((address_space(3))) unsigned int*)l, 16, 0, 0);
}

// -------- generic 32x32 transpose+cvt body ----------------------------------
__device__ __forceinline__ void transpose_body(const float* __restrict__ in,
                                               bf16* __restrict__ out,
                                               int K, int N, int nb, int kb, int rmap){
  __shared__ float tile[32][33];
  int tx = threadIdx.x, ty = threadIdx.y;   // 32 x 8
  #pragma unroll
  for (int j=0;j<4;j++)
    tile[ty+8*j][tx] = in[(size_t)(kb+ty+8*j)*N + nb+tx];
  __syncthreads();
  #pragma unroll
  for (int j=0;j<4;j++){
    int n = nb+ty+8*j;
    int R = (rmap==0) ? n : (((n>>4)<<5) + (n&15) + (rmap==2 ? 16 : 0));
    out[(size_t)R*K + kb+tx] = f2bf(tile[tx][ty+8*j]);
  }
}

// identity transpose (inproj, enc)
__global__ __launch_bounds__(256) void k_transpose_cvt(const float* __restrict__ in,
                                                       bf16* __restrict__ out,
                                                       int K, int N){
  transpose_body(in, out, K, N, blockIdx.x*32, blockIdx.y*32, 0);
}

// all 7 weight matrices of one layer in a single launch (14592 blocks)
__global__ __launch_bounds__(256) void k_transpose_layer(
    const float* __restrict__ wq, const float* __restrict__ wk,
    const float* __restrict__ wv, const float* __restrict__ wo,
    const float* __restrict__ wg, const float* __restrict__ wu,
    const float* __restrict__ wd,
    bf16* __restrict__ wqkvT, bf16* __restrict__ woT,
    bf16* __restrict__ wguT, bf16* __restrict__ wdT){
  int id = blockIdx.x;
  const float* in; bf16* out; int K=1024, N=1024, nbx=32, rmap=0;
  if (id < 1024){ in=wq; out=wqkvT; }
  else if (id < 1152){ id-=1024; in=wk; out=wqkvT+(size_t)1024*1024; N=128; nbx=4; }
  else if (id < 1280){ id-=1152; in=wv; out=wqkvT+(size_t)1152*1024; N=128; nbx=4; }
  else if (id < 2304){ id-=1280; in=wo; out=woT; }
  else if (id < 6400){ id-=2304; in=wg; out=wguT; N=4096; nbx=128; rmap=1; }
  else if (id < 10496){ id-=6400; in=wu; out=wguT; N=4096; nbx=128; rmap=2; }
  else { id-=10496; in=wd; out=wdT; K=4096; N=1024; nbx=32; }
  transpose_body(in, out, K, N, (id % nbx)*32, (id / nbx)*32, rmap);
}

// -------- elementwise fp32 -> bf16 (audio features) -------------------------
__global__ __launch_bounds__(256) void k_cvt_bf16(const float* __restrict__ in,
                                                  bf16* __restrict__ out, int n4){
  int i = blockIdx.x*blockDim.x + threadIdx.x;
  if (i < n4){
    float4 v = ((const float4*)in)[i];
    out[4*i+0]=f2bf(v.x); out[4*i+1]=f2bf(v.y);
    out[4*i+2]=f2bf(v.z); out[4*i+3]=f2bf(v.w);
  }
}

// -------- write special token into h row n*5 (bf16) -------------------------
__global__ __launch_bounds__(256) void k_fill_special(const float* __restrict__ sp,
                                                      bf16* __restrict__ h){
  int i = blockIdx.x*blockDim.x + threadIdx.x;   // NSAMP*1024 threads
  int n = i >> 10, c = i & 1023;
  h[(size_t)n*QL*1024 + c] = f2bf(sp[c]);
}

// -------- RoPE cos/sin tables, scale HD^-0.25 baked in ----------------------
__global__ void k_rope_tab(float* __restrict__ ctab, float* __restrict__ stab){
  int i = threadIdx.x;                 // 320 threads: t=i>>6, d=i&63
  int t = i >> 6, d = i & 63, j = d & 31;
  float invf = __expf(-((float)j/32.0f) * logf(10000.0f));
  float ang  = (float)t * invf;
  const float s = 0.35355339059327373f;   // 64^-0.25
  ctab[i] = cosf(ang)*s;
  stab[i] = sinf(ang)*s;
}

// -------- RMSNorm: bf16 in -> bf16 out --------------------------------------
__global__ __launch_bounds__(256) void k_rmsnorm(const bf16* __restrict__ in,
                                                 const float* __restrict__ w,
                                                 bf16* __restrict__ out,
                                                 int nrows, int in_stride){
  int row  = blockIdx.x*4 + (threadIdx.x>>6);
  int lane = threadIdx.x & 63;
  if (row >= nrows) return;
  const bf16* p = in + (size_t)row*in_stride;
  float f[16]; float ss = 0.f;
  #pragma unroll
  for (int i=0;i<2;i++){
    u16x8 v = *(const u16x8*)(p + i*512 + lane*8);
    #pragma unroll
    for (int j=0;j<8;j++){ float x = bfu2f(v[j]); f[i*8+j] = x; ss += x*x; }
  }
  #pragma unroll
  for (int off=32; off; off>>=1) ss += __shfl_xor(ss, off);
  float inv = rsqrtf(ss * (1.0f/1024.0f) + 1e-5f);
  const float4* w4 = (const float4*)w;
  bf16* op = out + (size_t)row*1024;
  #pragma unroll
  for (int i=0;i<2;i++){
    int c = i*512 + lane*8;
    float4 wa = w4[c/4], wb = w4[c/4 + 1];
    u16x8 o;
    o[0]=f2bfu(f[i*8+0]*inv*wa.x); o[1]=f2bfu(f[i*8+1]*inv*wa.y);
    o[2]=f2bfu(f[i*8+2]*inv*wa.z); o[3]=f2bfu(f[i*8+3]*inv*wa.w);
    o[4]=f2bfu(f[i*8+4]*inv*wb.x); o[5]=f2bfu(f[i*8+5]*inv*wb.y);
    o[6]=f2bfu(f[i*8+6]*inv*wb.z); o[7]=f2bfu(f[i*8+7]*inv*wb.w);
    *(u16x8*)(op + c) = o;
  }
}

// -------- fused residual-add + RMSNorm --------------------------------------
// hn = h + add; if WRITEH: h = hn (bf16). out = rms(hn)*w.
template<bool WRITEH>
__global__ __launch_bounds__(256) void k_addnorm(bf16* __restrict__ h,
                                                 const float* __restrict__ w,
                                                 const bf16* add,
                                                 bf16* out,
                                                 int nrows, int in_stride){
  int row  = blockIdx.x*4 + (threadIdx.x>>6);
  int lane = threadIdx.x & 63;
  if (row >= nrows) return;
  bf16* hp = h + (size_t)row*in_stride;
  const bf16* ap = add + (size_t)row*in_stride;
  float f[16]; float ss = 0.f;
  u16x8 hv[2], av[2];
  #pragma unroll
  for (int i=0;i<2;i++){
    hv[i] = *(const u16x8*)(hp + i*512 + lane*8);
    av[i] = *(const u16x8*)(ap + i*512 + lane*8);
  }
  #pragma unroll
  for (int i=0;i<2;i++)
    #pragma unroll
    for (int j=0;j<8;j++){
      float x = bfu2f(hv[i][j]) + bfu2f(av[i][j]);
      f[i*8+j] = x; ss += x*x;
    }
  if constexpr (WRITEH){
    #pragma unroll
    for (int i=0;i<2;i++){
      u16x8 o;
      #pragma unroll
      for (int j=0;j<8;j++) o[j] = f2bfu(f[i*8+j]);
      *(u16x8*)(hp + i*512 + lane*8) = o;
    }
  }
  #pragma unroll
  for (int off=32; off; off>>=1) ss += __shfl_xor(ss, off);
  float inv = rsqrtf(ss * (1.0f/1024.0f) + 1e-5f);
  const float4* w4 = (const float4*)w;
  bf16* op = out + (size_t)row*1024;
  #pragma unroll
  for (int i=0;i<2;i++){
    int c = i*512 + lane*8;
    float4 wa = w4[c/4], wb = w4[c/4 + 1];
    u16x8 o;
    o[0]=f2bfu(f[i*8+0]*inv*wa.x); o[1]=f2bfu(f[i*8+1]*inv*wa.y);
    o[2]=f2bfu(f[i*8+2]*inv*wa.z); o[3]=f2bfu(f[i*8+3]*inv*wa.w);
    o[4]=f2bfu(f[i*8+4]*inv*wb.x); o[5]=f2bfu(f[i*8+5]*inv*wb.y);
    o[6]=f2bfu(f[i*8+6]*inv*wb.z); o[7]=f2bfu(f[i*8+7]*inv*wb.w);
    *(u16x8*)(op + c) = o;
  }
}

// ======================= 256x256 8-phase bf16 MFMA GEMM ======================
// C[M,N] = A[M,K] @ B^T (B stored [N][K] bf16). 512 threads, 8 waves (2M x 4N).
// BK=64, double-buffered 128KiB LDS, 3-bit XOR swizzle (bank-conflict-free,
// verified round 4). Round-7: all 24 ds_read_b128 for a K-tile issued at tile
// start; counted lgkmcnt(12)/lgkmcnt(0) before the first two MFMA quadrants;
// quadrants Q01/Q11 run wait-free. Staging of tile t+2 into the live buffer
// still happens strictly after all waves pass the lgkmcnt(0)+barrier.
// OUTMODE: 0 fp32 store, 1 bf16 store, 2 silu(g)*u from 16-col-interleaved GU.
template<int OUTMODE>
__device__ __forceinline__ void gemm256_impl(const bf16* __restrict__ A,
                                             const bf16* __restrict__ B,
                                             float* __restrict__ Cf,
                                             bf16* __restrict__ Cb,
                                             int M, int N, int K, int ldc){
  __shared__ bf16 lds[65536];          // 128 KiB: buf p at byte p*65536
  char* ldsb = (char*)lds;
  const int tid  = threadIdx.x;
  const int wid  = tid >> 6, lane = tid & 63;
  const int wr   = wid >> 2, wc  = wid & 3;
  const int fr   = lane & 15, fq = lane >> 4;
  const int swz = (fr & 7) << 4;
  const int cs0 = (fq*16) ^ swz;
  const int cs1 = (fq*16 + 64) ^ swz;
  const int srcR = lane >> 3;
  const int srcC = ((lane & 7) ^ srcR) * 8;

  const int bm0 = blockIdx.x*256, bn0 = blockIdx.y*256;
  const bf16* gA = A + (size_t)bm0*K;
  const bf16* gB = B + (size_t)bn0*K;
  const int nt = K >> 6;

  const int aOff = (wr ? 16384 : 0);
  const int bOff = 32768 + ((wc>>1) ? 16384 : 0) + (wc&1)*8192;
  const char* aB0 = ldsb + aOff + fr*128 + cs0;
  const char* aB1 = ldsb + aOff + fr*128 + cs1;
  const char* bB0 = ldsb + bOff + fr*128 + cs0;
  const char* bB1 = ldsb + bOff + fr*128 + cs1;

  f32x4 acc[8][4] = {};
  bf16x8 aF[8][2], bF[4][2];

#define STAGE(p, t, h) {                                                        \
    const bf16* G_ = ((h) < 2) ? gA : gB;                                       \
    const int rb_ = ((h)&1) ? 128 : 0;                                          \
    const int k0_ = (t) << 6;                                                   \
    _Pragma("unroll")                                                           \
    for (int j_=0;j_<2;j_++){                                                   \
      int blk_ = j_*8 + wid;                                                    \
      gload16(G_ + (size_t)(rb_ + blk_*8 + srcR)*K + k0_ + srcC,               \
              ldsb + (p)*65536 + (h)*16384 + blk_*1024);                        \
    }                                                                           \
  }
#define RD_A(p, m0_) {                                                          \
    _Pragma("unroll")                                                           \
    for (int m_=0;m_<4;m_++)                                                    \
      _Pragma("unroll")                                                         \
      for (int ks_=0;ks_<2;ks_++)                                               \
        aF[(m0_)+m_][ks_] = *(const bf16x8*)((ks_ ? aB1 : aB0) + (p)*65536 + ((m0_)+m_)*2048); \
  }
#define RD_B(p, n0_) {                                                          \
    _Pragma("unroll")                                                           \
    for (int n_=0;n_<2;n_++)                                                    \
      _Pragma("unroll")                                                         \
      for (int ks_=0;ks_<2;ks_++)                                               \
        bF[(n0_)+n_][ks_] = *(const bf16x8*)((ks_ ? bB1 : bB0) + (p)*65536 + ((n0_)+n_)*2048); \
  }
#define MM(qm_, qn_) {                                                          \
    _Pragma("unroll")                                                           \
    for (int m_=0;m_<4;m_++)                                                    \
      _Pragma("unroll")                                                         \
      for (int n_=0;n_<2;n_++)                                                  \
        _Pragma("unroll")                                                       \
        for (int ks_=0;ks_<2;ks_++)                                             \
          acc[(qm_)*4+m_][(qn_)*2+n_] = __builtin_amdgcn_mfma_f32_16x16x32_bf16( \
              aF[(qm_)*4+m_][ks_], bF[(qn_)*2+n_][ks_], acc[(qm_)*4+m_][(qn_)*2+n_], 0,0,0); \
  }
#define SBAR   __builtin_amdgcn_sched_barrier(0)
#define BAR    __builtin_amdgcn_s_barrier()

  STAGE(0, 0, 0); STAGE(0, 0, 1); STAGE(0, 0, 2); STAGE(0, 0, 3);
  if (nt > 1){ STAGE(1, 1, 0); STAGE(1, 1, 1); STAGE(1, 1, 2); STAGE(1, 1, 3); }
  if (nt > 1) asm volatile("s_waitcnt vmcnt(8)" ::: "memory");
  else        asm volatile("s_waitcnt vmcnt(0)" ::: "memory");
  BAR;

  for (int t = 0; t < nt; t++){
    const int cur = t & 1;
    const bool pf = (t + 2) < nt;
    // issue all 24 tile reads: Q00 operands (12) pinned first
    RD_A(cur, 0); RD_B(cur, 0);
    SBAR;
    RD_A(cur, 4); RD_B(cur, 2);
    BAR;
    // P0: wait first 12 reads, MFMA Q(0,0)
    SBAR; asm volatile("s_waitcnt lgkmcnt(12)" ::: "memory"); SBAR;
    __builtin_amdgcn_s_setprio(1); MM(0,0); __builtin_amdgcn_s_setprio(0);
    BAR;
    // P1: wait rest, MFMA Q(1,0)  (all LDS reads of this tile now complete)
    SBAR; asm volatile("s_waitcnt lgkmcnt(0)" ::: "memory"); SBAR;
    __builtin_amdgcn_s_setprio(1); MM(1,0); __builtin_amdgcn_s_setprio(0);
    BAR;
    // P2: stage A-half0 of t+2 (A region fully read by all waves), MFMA Q(0,1)
    if (pf) STAGE(cur, t+2, 0);
    __builtin_amdgcn_s_setprio(1); MM(0,1); __builtin_amdgcn_s_setprio(0);
    BAR;
    // P3: stage rest of t+2, MFMA Q(1,1), counted vmcnt
    if (pf){ STAGE(cur, t+2, 1); STAGE(cur, t+2, 2); STAGE(cur, t+2, 3); }
    __builtin_amdgcn_s_setprio(1); MM(1,1); __builtin_amdgcn_s_setprio(0);
    if (t + 1 < nt){
      if (pf) asm volatile("s_waitcnt vmcnt(8)" ::: "memory");
      else    asm volatile("s_waitcnt vmcnt(0)" ::: "memory");
    }
    BAR;
  }

  #pragma unroll
  for (int m=0;m<8;m++){
    if constexpr (OUTMODE == 2){
      #pragma unroll
      for (int n2=0;n2<2;n2++){
        #pragma unroll
        for (int i=0;i<4;i++){
          int row = bm0 + wr*128 + m*16 + fq*4 + i;
          int col = (bn0>>1) + wc*32 + n2*16 + fr;
          float g = acc[m][n2*2][i], u = acc[m][n2*2+1][i];
          Cb[(size_t)row*ldc + col] = f2bf((g / (1.0f + __expf(-g))) * u);
        }
      }
    } else {
      #pragma unroll
      for (int n=0;n<4;n++){
        #pragma unroll
        for (int i=0;i<4;i++){
          int row = bm0 + wr*128 + m*16 + fq*4 + i;
          int col = bn0 + wc*64 + n*16 + fr;
          size_t idx = (size_t)row*ldc + col;
          if constexpr (OUTMODE == 0) Cf[idx] = acc[m][n][i];
          else                        Cb[idx] = f2bf(acc[m][n][i]);
        }
      }
    }
  }
#undef STAGE
#undef RD_A
#undef RD_B
#undef MM
#undef SBAR
#undef BAR
}

// distinct symbols per role for unambiguous rocprof attribution
__global__ __launch_bounds__(512) void k_gemm_qkv(const bf16* A, const bf16* B, bf16* Cb, int M, int N, int K, int ldc){
  gemm256_impl<1>(A, B, nullptr, Cb, M, N, K, ldc);
}
__global__ __launch_bounds__(512) void k_gemm_wo(const bf16* A, const bf16* B, bf16* Cb, int M, int N, int K, int ldc){
  gemm256_impl<1>(A, B, nullptr, Cb, M, N, K, ldc);
}
__global__ __launch_bounds__(512) void k_gemm_gu(const bf16* A, const bf16* B, bf16* Cb, int M, int N, int K, int ldc){
  gemm256_impl<2>(A, B, nullptr, Cb, M, N, K, ldc);
}
__global__ __launch_bounds__(512) void k_gemm_down(const bf16* A, const bf16* B, bf16* Cb, int M, int N, int K, int ldc){
  gemm256_impl<1>(A, B, nullptr, Cb, M, N, K, ldc);
}
__global__ __launch_bounds__(512) void k_gemm_out(const bf16* A, const bf16* B, float* Cf, int M, int N, int K, int ldc){
  gemm256_impl<0>(A, B, Cf, nullptr, M, N, K, ldc);
}

// -------- small 128-tile GEMM (embed only: K=64), bf16 out + row remap ------
__global__ __launch_bounds__(256) void k_gemm_embed(const bf16* __restrict__ A,
                                                    const bf16* __restrict__ B0,
                                                    bf16* __restrict__ Cb,
                                                    int M, int N, int K, int ldc){
  constexpr int BM = 128, BN = 128, BK = 32;
  constexpr int WN = BN/2, NR = WN/16, MR = 4;
  __shared__ bf16 lA[BM*BK];
  __shared__ bf16 lB[BN*BK];
  int wid = threadIdx.x >> 6, lane = threadIdx.x & 63;
  int wr = wid >> 1, wc = wid & 1;
  int bm0 = blockIdx.x * BM, bn0 = blockIdx.y * BN;
  int fr = lane & 15, fq = lane >> 4;
  int rowInCh = lane >> 2, colInCh = (lane & 3)*8;
  f32x4 acc[MR][NR] = {};
  const bf16* gA = A + (size_t)bm0*K;
  const bf16* gB = B0 + (size_t)bn0*K;
  for (int k0 = 0; k0 < K; k0 += BK){
    #pragma unroll
    for (int i = 0; i < BM/64; i++){
      int ch = wid + 4*i;
      gload16(gA + (size_t)(16*ch + rowInCh)*K + k0 + colInCh, lA + 16*ch*BK);
    }
    #pragma unroll
    for (int i = 0; i < BN/64; i++){
      int ch = wid + 4*i;
      gload16(gB + (size_t)(16*ch + rowInCh)*K + k0 + colInCh, lB + 16*ch*BK);
    }
    __syncthreads();
    bf16x8 af[MR];
    #pragma unroll
    for (int m=0;m<MR;m++)
      af[m] = *(const bf16x8*)(lA + (wr*64 + m*16 + fr)*BK + fq*8);
    #pragma unroll
    for (int n=0;n<NR;n++){
      bf16x8 bfr = *(const bf16x8*)(lB + (wc*WN + n*16 + fr)*BK + fq*8);
      #pragma unroll
      for (int m=0;m<MR;m++)
        acc[m][n] = __builtin_amdgcn_mfma_f32_16x16x32_bf16(af[m], bfr, acc[m][n], 0,0,0);
    }
    __syncthreads();
  }
  #pragma unroll
  for (int m=0;m<MR;m++)
    #pragma unroll
    for (int n=0;n<NR;n++)
      #pragma unroll
      for (int i=0;i<4;i++){
        int row = bm0 + wr*64 + m*16 + fq*4 + i;
        int col = bn0 + wc*WN + n*16 + fr;
        size_t orow = (size_t)(row + (row>>2) + 1);      // skip special token rows
        Cb[orow*(size_t)ldc + col] = f2bf(acc[m][n][i]);
      }
}

// -------- attention: one wave per (sample, head); QLEN=5, HD=64 -------------
// reads packed qkv [Rc][1280]; writes output into xn rows [Rc][1024]
__global__ __launch_bounds__(256) void k_attn(const bf16* __restrict__ qkv,
                                              bf16* __restrict__ xn,
                                              const float* __restrict__ ctab,
                                              const float* __restrict__ stab){
  int gw   = blockIdx.x*4 + (threadIdx.x>>6);
  int lane = threadIdx.x & 63;
  int sample = gw >> 4, head = gw & 15, kvh = head >> 3;

  float qf[QL], kf[QL], vf[QL];
  #pragma unroll
  for (int t=0;t<QL;t++){
    size_t r = (size_t)(sample*QL + t)*1280;
    qf[t] = bf2f(qkv[r + head*64 + lane]);
    kf[t] = bf2f(qkv[r + 1024 + kvh*64 + lane]);
    vf[t] = bf2f(qkv[r + 1152 + kvh*64 + lane]);
  }
  #pragma unroll
  for (int t=0;t<QL;t++){
    float c = ctab[t*64+lane], s = stab[t*64+lane];
    float qo = __shfl_xor(qf[t], 32);
    float ko = __shfl_xor(kf[t], 32);
    float rq = (lane < 32) ? -qo : qo;
    float rk = (lane < 32) ? -ko : ko;
    qf[t] = qf[t]*c + rq*s;
    kf[t] = kf[t]*c + rk*s;
  }
  float p[QL][QL];
  #pragma unroll
  for (int i=0;i<QL;i++)
    #pragma unroll
    for (int j=0;j<QL;j++) p[i][j] = qf[i]*kf[j];
  #pragma unroll
  for (int off=32; off; off>>=1){
    #pragma unroll
    for (int i=0;i<QL;i++)
      #pragma unroll
      for (int j=0;j<QL;j++) p[i][j] += __shfl_xor(p[i][j], off);
  }
  #pragma unroll
  for (int i=0;i<QL;i++){
    float mx = p[i][0];
    #pragma unroll
    for (int j=1;j<QL;j++) mx = fmaxf(mx, p[i][j]);
    float sum = 0.f;
    #pragma unroll
    for (int j=0;j<QL;j++){ p[i][j] = __expf(p[i][j]-mx); sum += p[i][j]; }
    float rs = 1.0f/sum;
    float o = 0.f;
    #pragma unroll
    for (int j=0;j<QL;j++) o += p[i][j]*vf[j];
    xn[((size_t)(sample*QL+i))*1024 + head*64 + lane] = f2bf(o*rs);
  }
}

__global__ void k_diag(float* out, float v){ out[0] = v; }

extern "C" void kernel_launch(void* const* d_in, const int* in_sizes, int n_in,
                              void* d_out, int out_size, void* d_ws, size_t ws_size,
                              hipStream_t stream){
  const float* audio = (const float*)d_in[0];
  const float* sp    = (const float*)d_in[1];
  const float* inpw  = (const float*)d_in[2];
  const float* ln1   = (const float*)d_in[3];
  const float* wq    = (const float*)d_in[4];
  const float* wk    = (const float*)d_in[5];
  const float* wv    = (const float*)d_in[6];
  const float* wo    = (const float*)d_in[7];
  const float* ln2   = (const float*)d_in[8];
  const float* wg    = (const float*)d_in[9];
  const float* wu    = (const float*)d_in[10];
  const float* wd    = (const float*)d_in[11];
  const float* fnw   = (const float*)d_in[12];
  const float* enc   = (const float*)d_in[13];
  float* out = (float*)d_out;
  char* ws = (char*)d_ws;

  // ---- adaptive workspace plan: ONE structure for all tiers ---------------
  // tiers differ only in chunk sizes (CH for qkv/attn/wo, RM for gu/down).
  size_t o_h=0,o_wqkv=0,o_wo=0,o_wgu=0,o_wd=0,o_ct=0,o_st=0,o_xn=0,o_u=0;
  size_t CH=0, RM=0;
  const size_t tierCH[6] = {8192, 8192, 8192, 4096, 2048, 1024};
  const size_t tierRM[6] = {40960, 20480, 10240, 10240, 5120, 2560};
  for (int t=0;t<6;t++){
    size_t ch = tierCH[t], rm = tierRM[t];
    size_t off = 0;
    auto al = [&](size_t b){ size_t o=off; off=(off+b+255)&~(size_t)255; return o; };
    o_h   = al((size_t)MTOK*1024*2);
    o_wqkv= al((size_t)1280*1024*2);
    o_wo  = al((size_t)1024*1024*2);
    o_wgu = al((size_t)8192*1024*2);
    o_wd  = al((size_t)1024*4096*2);
    o_ct  = al(QL*64*4);
    o_st  = al(QL*64*4);
    o_xn  = al((size_t)MTOK*1024*2);
    size_t qkvB = ch*QL*1280*2, aoB = ch*QL*1024*2;
    size_t actB = rm*4096*2,    xcB = (size_t)NSAMP*1024*2;
    size_t ub = qkvB; if (aoB>ub) ub=aoB; if (actB>ub) ub=actB; if (xcB>ub) ub=xcB;
    o_u   = al(ub);
    if (off <= ws_size){ CH = ch; RM = rm; break; }
  }
  if (CH == 0){ k_diag<<<1,1,0,stream>>>(out, (float)ws_size); return; }

  bf16*  h     = (bf16*)(ws + o_h);
  bf16*  wqkvT = (bf16*)(ws + o_wqkv);
  bf16*  woT   = (bf16*)(ws + o_wo);
  bf16*  wguT  = (bf16*)(ws + o_wgu);
  bf16*  wdT   = (bf16*)(ws + o_wd);
  float* ctab  = (float*)(ws + o_ct);
  float* stab  = (float*)(ws + o_st);
  bf16*  xn    = (bf16*)(ws + o_xn);
  bf16*  ubuf  = (bf16*)(ws + o_u);      // union: qkv / ao / act / xc / af16
  bf16*  inprojT = wqkvT;                // alias: pre-loop only
  bf16*  encT    = wguT;                 // alias: post-loop only

  dim3 tb(32,8);
  k_rope_tab<<<1, 320, 0, stream>>>(ctab, stab);
  k_transpose_cvt<<<dim3(32, 2), tb, 0, stream>>>(inpw, inprojT, 64, 1024);
  k_cvt_bf16<<<(32768*64/4)/256, 256, 0, stream>>>(audio, ubuf, 32768*64/4);
  k_fill_special<<<NSAMP*1024/256, 256, 0, stream>>>(sp, h);
  k_gemm_embed<<<dim3(32768/128, 1024/128), 256, 0, stream>>>(
      ubuf, inprojT, h, 32768, 1024, 64, 1024);

  for (int l=0;l<4;l++){
    k_transpose_layer<<<14592, tb, 0, stream>>>(
        wq + (size_t)l*1024*1024, wk + (size_t)l*1024*128, wv + (size_t)l*1024*128,
        wo + (size_t)l*1024*1024, wg + (size_t)l*1024*4096, wu + (size_t)l*1024*4096,
        wd + (size_t)l*4096*1024, wqkvT, woT, wguT, wdT);

    // ln1: layer 0 from h alone; else h += xn (prev down-out), norm -> xn
    if (l == 0)
      k_rmsnorm<<<MTOK/4, 256, 0, stream>>>(h, ln1, xn, MTOK, 1024);
    else
      k_addnorm<true><<<MTOK/4, 256, 0, stream>>>(h, ln1 + l*1024, xn, xn, MTOK, 1024);

    // qkv + attention, chunked by CH samples (attn writes back into xn rows)
    for (size_t c0 = 0; c0 < NSAMP; c0 += CH){
      size_t r0 = c0*QL, Rc = CH*QL;
      k_gemm_qkv<<<dim3(Rc/256, 5), 512, 0, stream>>>(
          xn + r0*1024, wqkvT, ubuf, (int)Rc, 1280, 1024, 1280);
      k_attn<<<CH*16/4, 256, 0, stream>>>(ubuf, xn + r0*1024, ctab, stab);
    }
    // wo + addnorm2, chunked by CH (pure-store epilogue; ao in union)
    for (size_t c0 = 0; c0 < NSAMP; c0 += CH){
      size_t r0 = c0*QL, Rc = CH*QL;
      k_gemm_wo<<<dim3(Rc/256, 4), 512, 0, stream>>>(
          xn + r0*1024, woT, ubuf, (int)Rc, 1024, 1024, 1024);
      k_addnorm<true><<<Rc/4, 256, 0, stream>>>(
          h + r0*1024, ln2 + l*1024, ubuf, xn + r0*1024, (int)Rc, 1024);
    }
    // MLP, chunked by RM rows (down writes back into xn; residual deferred)
    for (size_t m0 = 0; m0 < MTOK; m0 += RM){
      k_gemm_gu<<<dim3(RM/256, 32), 512, 0, stream>>>(
          xn + m0*1024, wguT, ubuf, (int)RM, 8192, 1024, 4096);
      k_gemm_down<<<dim3(RM/256, 4), 512, 0, stream>>>(
          ubuf, wdT, xn + m0*1024, (int)RM, 1024, 4096, 1024);
    }
  }

  k_transpose_cvt<<<dim3(64, 32), tb, 0, stream>>>(enc, encT, 1024, 2048);
  // final: rows n*5 only: hn = h + xn (last down-out), norm -> compact xc
  k_addnorm<false><<<NSAMP/4, 256, 0, stream>>>(h, fnw, xn, ubuf, NSAMP, QL*1024);
  k_gemm_out<<<dim3(NSAMP/256, 2048/256), 512, 0, stream>>>(
      ubuf, encT, out, NSAMP, 2048, 1024, 2048);
}

// Round 8
// 7082.476 us; speedup vs baseline: 1.2535x; 1.2535x over previous
//
#include <hip/hip_runtime.h>
#include <hip/hip_bf16.h>

#define NSAMP 8192
#define QL 5
#define MTOK (NSAMP*QL)   // 40960 tokens

typedef __hip_bfloat16 bf16;
typedef __attribute__((ext_vector_type(8))) __bf16 bf16x8;
typedef __attribute__((ext_vector_type(8))) unsigned short u16x8;
typedef __attribute__((ext_vector_type(4))) float f32x4;

__device__ __forceinline__ float bfu2f(unsigned short u){ return __uint_as_float(((unsigned)u)<<16); }
__device__ __forceinline__ float bf2f(bf16 v){ return __bfloat162float(v); }
__device__ __forceinline__ bf16  f2bf(float v){ return __float2bfloat16(v); }
__device__ __forceinline__ unsigned short f2bfu(float v){
  __hip_bfloat16 b = __float2bfloat16(v);
  return __builtin_bit_cast(unsigned short, b);
}

__device__ __forceinline__ void gload16(const void* g, void* l){
  __builtin_amdgcn_global_load_lds(
      (const __attribute__((address_space(1))) unsigned int*)g,
      (__attribute__((address_space(3))) unsigned int*)l, 16, 0, 0);
}

// -------- generic 32x32 transpose+cvt body ----------------------------------
__device__ __forceinline__ void transpose_body(const float* __restrict__ in,
                                               bf16* __restrict__ out,
                                               int K, int N, int nb, int kb, int rmap){
  __shared__ float tile[32][33];
  int tx = threadIdx.x, ty = threadIdx.y;   // 32 x 8
  #pragma unroll
  for (int j=0;j<4;j++)
    tile[ty+8*j][tx] = in[(size_t)(kb+ty+8*j)*N + nb+tx];
  __syncthreads();
  #pragma unroll
  for (int j=0;j<4;j++){
    int n = nb+ty+8*j;
    int R = (rmap==0) ? n : (((n>>4)<<5) + (n&15) + (rmap==2 ? 16 : 0));
    out[(size_t)R*K + kb+tx] = f2bf(tile[tx][ty+8*j]);
  }
}

__global__ __launch_bounds__(256) void k_transpose_cvt(const float* __restrict__ in,
                                                       bf16* __restrict__ out,
                                                       int K, int N){
  transpose_body(in, out, K, N, blockIdx.x*32, blockIdx.y*32, 0);
}

// all 7 weight matrices of one layer in a single launch (14592 blocks)
__global__ __launch_bounds__(256) void k_transpose_layer(
    const float* __restrict__ wq, const float* __restrict__ wk,
    const float* __restrict__ wv, const float* __restrict__ wo,
    const float* __restrict__ wg, const float* __restrict__ wu,
    const float* __restrict__ wd,
    bf16* __restrict__ wqkvT, bf16* __restrict__ woT,
    bf16* __restrict__ wguT, bf16* __restrict__ wdT){
  int id = blockIdx.x;
  const float* in; bf16* out; int K=1024, N=1024, nbx=32, rmap=0;
  if (id < 1024){ in=wq; out=wqkvT; }
  else if (id < 1152){ id-=1024; in=wk; out=wqkvT+(size_t)1024*1024; N=128; nbx=4; }
  else if (id < 1280){ id-=1152; in=wv; out=wqkvT+(size_t)1152*1024; N=128; nbx=4; }
  else if (id < 2304){ id-=1280; in=wo; out=woT; }
  else if (id < 6400){ id-=2304; in=wg; out=wguT; N=4096; nbx=128; rmap=1; }
  else if (id < 10496){ id-=6400; in=wu; out=wguT; N=4096; nbx=128; rmap=2; }
  else { id-=10496; in=wd; out=wdT; K=4096; N=1024; nbx=32; }
  transpose_body(in, out, K, N, (id % nbx)*32, (id / nbx)*32, rmap);
}

// -------- elementwise fp32 -> bf16 (audio features) -------------------------
__global__ __launch_bounds__(256) void k_cvt_bf16(const float* __restrict__ in,
                                                  bf16* __restrict__ out, int n4){
  int i = blockIdx.x*blockDim.x + threadIdx.x;
  if (i < n4){
    float4 v = ((const float4*)in)[i];
    out[4*i+0]=f2bf(v.x); out[4*i+1]=f2bf(v.y);
    out[4*i+2]=f2bf(v.z); out[4*i+3]=f2bf(v.w);
  }
}

// -------- write special token into h row n*5 (bf16) -------------------------
__global__ __launch_bounds__(256) void k_fill_special(const float* __restrict__ sp,
                                                      bf16* __restrict__ h){
  int i = blockIdx.x*blockDim.x + threadIdx.x;   // NSAMP*1024 threads
  int n = i >> 10, c = i & 1023;
  h[(size_t)n*QL*1024 + c] = f2bf(sp[c]);
}

// -------- RoPE cos/sin tables, scale HD^-0.25 baked in ----------------------
__global__ void k_rope_tab(float* __restrict__ ctab, float* __restrict__ stab){
  int i = threadIdx.x;                 // 320 threads: t=i>>6, d=i&63
  int t = i >> 6, d = i & 63, j = d & 31;
  float invf = __expf(-((float)j/32.0f) * logf(10000.0f));
  float ang  = (float)t * invf;
  const float s = 0.35355339059327373f;   // 64^-0.25
  ctab[i] = cosf(ang)*s;
  stab[i] = sinf(ang)*s;
}

// -------- RMSNorm: bf16 in (stride) -> bf16 out (stride 1024) ---------------
__global__ __launch_bounds__(256) void k_rmsnorm(const bf16* __restrict__ in,
                                                 const float* __restrict__ w,
                                                 bf16* __restrict__ out,
                                                 int nrows, int in_stride){
  int row  = blockIdx.x*4 + (threadIdx.x>>6);
  int lane = threadIdx.x & 63;
  if (row >= nrows) return;
  const bf16* p = in + (size_t)row*in_stride;
  float f[16]; float ss = 0.f;
  #pragma unroll
  for (int i=0;i<2;i++){
    u16x8 v = *(const u16x8*)(p + i*512 + lane*8);
    #pragma unroll
    for (int j=0;j<8;j++){ float x = bfu2f(v[j]); f[i*8+j] = x; ss += x*x; }
  }
  #pragma unroll
  for (int off=32; off; off>>=1) ss += __shfl_xor(ss, off);
  float inv = rsqrtf(ss * (1.0f/1024.0f) + 1e-5f);
  const float4* w4 = (const float4*)w;
  bf16* op = out + (size_t)row*1024;
  #pragma unroll
  for (int i=0;i<2;i++){
    int c = i*512 + lane*8;
    float4 wa = w4[c/4], wb = w4[c/4 + 1];
    u16x8 o;
    o[0]=f2bfu(f[i*8+0]*inv*wa.x); o[1]=f2bfu(f[i*8+1]*inv*wa.y);
    o[2]=f2bfu(f[i*8+2]*inv*wa.z); o[3]=f2bfu(f[i*8+3]*inv*wa.w);
    o[4]=f2bfu(f[i*8+4]*inv*wb.x); o[5]=f2bfu(f[i*8+5]*inv*wb.y);
    o[6]=f2bfu(f[i*8+6]*inv*wb.z); o[7]=f2bfu(f[i*8+7]*inv*wb.w);
    *(u16x8*)(op + c) = o;
  }
}

// -------- fused residual-add + RMSNorm: h += add (write), out = rms(h)*w ----
__global__ __launch_bounds__(256) void k_addnorm(bf16* __restrict__ h,
                                                 const float* __restrict__ w,
                                                 const bf16* __restrict__ add,
                                                 bf16* __restrict__ out,
                                                 int nrows){
  int row  = blockIdx.x*4 + (threadIdx.x>>6);
  int lane = threadIdx.x & 63;
  if (row >= nrows) return;
  bf16* hp = h + (size_t)row*1024;
  const bf16* ap = add + (size_t)row*1024;
  float f[16]; float ss = 0.f;
  u16x8 hv[2], av[2];
  #pragma unroll
  for (int i=0;i<2;i++){
    hv[i] = *(const u16x8*)(hp + i*512 + lane*8);
    av[i] = *(const u16x8*)(ap + i*512 + lane*8);
  }
  #pragma unroll
  for (int i=0;i<2;i++)
    #pragma unroll
    for (int j=0;j<8;j++){
      float x = bfu2f(hv[i][j]) + bfu2f(av[i][j]);
      f[i*8+j] = x; ss += x*x;
    }
  #pragma unroll
  for (int i=0;i<2;i++){
    u16x8 o;
    #pragma unroll
    for (int j=0;j<8;j++) o[j] = f2bfu(f[i*8+j]);
    *(u16x8*)(hp + i*512 + lane*8) = o;
  }
  #pragma unroll
  for (int off=32; off; off>>=1) ss += __shfl_xor(ss, off);
  float inv = rsqrtf(ss * (1.0f/1024.0f) + 1e-5f);
  const float4* w4 = (const float4*)w;
  bf16* op = out + (size_t)row*1024;
  #pragma unroll
  for (int i=0;i<2;i++){
    int c = i*512 + lane*8;
    float4 wa = w4[c/4], wb = w4[c/4 + 1];
    u16x8 o;
    o[0]=f2bfu(f[i*8+0]*inv*wa.x); o[1]=f2bfu(f[i*8+1]*inv*wa.y);
    o[2]=f2bfu(f[i*8+2]*inv*wa.z); o[3]=f2bfu(f[i*8+3]*inv*wa.w);
    o[4]=f2bfu(f[i*8+4]*inv*wb.x); o[5]=f2bfu(f[i*8+5]*inv*wb.y);
    o[6]=f2bfu(f[i*8+6]*inv*wb.z); o[7]=f2bfu(f[i*8+7]*inv*wb.w);
    *(u16x8*)(op + c) = o;
  }
}

// -------- plain residual add: h += d (bf16, fp32 intermediate) --------------
__global__ __launch_bounds__(256) void k_add(bf16* __restrict__ h,
                                             const bf16* __restrict__ d, int n8){
  int i = blockIdx.x*blockDim.x + threadIdx.x;
  if (i < n8){
    u16x8 a = *(const u16x8*)(h + (size_t)i*8);
    u16x8 b = *(const u16x8*)(d + (size_t)i*8);
    u16x8 o;
    #pragma unroll
    for (int j=0;j<8;j++) o[j] = f2bfu(bfu2f(a[j]) + bfu2f(b[j]));
    *(u16x8*)(h + (size_t)i*8) = o;
  }
}

// ======================= 256x256 bf16 MFMA GEMM (R4-proven schedule) =========
// C[M,N] = A[M,K] @ B^T (B stored [N][K] bf16). 512 threads, 8 waves (2M x 4N).
// BK=64, double-buffered 128KiB LDS, 3-bit XOR swizzle (bank-conflict-free,
// verified round 4: SQ_LDS_BANK_CONFLICT==0). Counted vmcnt(8), setprio.
// OUTMODE: 0 fp32 store, 1 bf16 store, 2 silu(g)*u from 16-col-interleaved GU.
template<int OUTMODE>
__device__ __forceinline__ void gemm256_impl(const bf16* __restrict__ A,
                                             const bf16* __restrict__ B,
                                             float* __restrict__ Cf,
                                             bf16* __restrict__ Cb,
                                             int M, int N, int K, int ldc){
  __shared__ bf16 lds[65536];          // 128 KiB: buf p at byte p*65536
  char* ldsb = (char*)lds;
  const int tid  = threadIdx.x;
  const int wid  = tid >> 6, lane = tid & 63;
  const int wr   = wid >> 2, wc  = wid & 3;
  const int fr   = lane & 15, fq = lane >> 4;
  const int swz = (fr & 7) << 4;
  const int cs0 = (fq*16) ^ swz;
  const int cs1 = (fq*16 + 64) ^ swz;
  const int srcR = lane >> 3;
  const int srcC = ((lane & 7) ^ srcR) * 8;

  const int bm0 = blockIdx.x*256, bn0 = blockIdx.y*256;
  const bf16* gA = A + (size_t)bm0*K;
  const bf16* gB = B + (size_t)bn0*K;
  const int nt = K >> 6;

  const int aOff = (wr ? 16384 : 0);
  const int bOff = 32768 + ((wc>>1) ? 16384 : 0) + (wc&1)*8192;
  const char* aB0 = ldsb + aOff + fr*128 + cs0;
  const char* aB1 = ldsb + aOff + fr*128 + cs1;
  const char* bB0 = ldsb + bOff + fr*128 + cs0;
  const char* bB1 = ldsb + bOff + fr*128 + cs1;

  f32x4 acc[8][4] = {};
  bf16x8 aF[8][2], bF[4][2];

#define STAGE(p, t, h) {                                                        \
    const bf16* G_ = ((h) < 2) ? gA : gB;                                       \
    const int rb_ = ((h)&1) ? 128 : 0;                                          \
    const int k0_ = (t) << 6;                                                   \
    _Pragma("unroll")                                                           \
    for (int j_=0;j_<2;j_++){                                                   \
      int blk_ = j_*8 + wid;                                                    \
      gload16(G_ + (size_t)(rb_ + blk_*8 + srcR)*K + k0_ + srcC,               \
              ldsb + (p)*65536 + (h)*16384 + blk_*1024);                        \
    }                                                                           \
  }
#define RD_A(p, m0_) {                                                          \
    _Pragma("unroll")                                                           \
    for (int m_=0;m_<4;m_++)                                                    \
      _Pragma("unroll")                                                         \
      for (int ks_=0;ks_<2;ks_++)                                               \
        aF[(m0_)+m_][ks_] = *(const bf16x8*)((ks_ ? aB1 : aB0) + (p)*65536 + ((m0_)+m_)*2048); \
  }
#define RD_B(p, n0_) {                                                          \
    _Pragma("unroll")                                                           \
    for (int n_=0;n_<2;n_++)                                                    \
      _Pragma("unroll")                                                         \
      for (int ks_=0;ks_<2;ks_++)                                               \
        bF[(n0_)+n_][ks_] = *(const bf16x8*)((ks_ ? bB1 : bB0) + (p)*65536 + ((n0_)+n_)*2048); \
  }
#define MM(qm_, qn_) {                                                          \
    _Pragma("unroll")                                                           \
    for (int m_=0;m_<4;m_++)                                                    \
      _Pragma("unroll")                                                         \
      for (int n_=0;n_<2;n_++)                                                  \
        _Pragma("unroll")                                                       \
        for (int ks_=0;ks_<2;ks_++)                                             \
          acc[(qm_)*4+m_][(qn_)*2+n_] = __builtin_amdgcn_mfma_f32_16x16x32_bf16( \
              aF[(qm_)*4+m_][ks_], bF[(qn_)*2+n_][ks_], acc[(qm_)*4+m_][(qn_)*2+n_], 0,0,0); \
  }
#define LGKM0  asm volatile("s_waitcnt lgkmcnt(0)" ::: "memory"); __builtin_amdgcn_sched_barrier(0)
#define BAR    __builtin_amdgcn_s_barrier()

  STAGE(0, 0, 0); STAGE(0, 0, 1); STAGE(0, 0, 2); STAGE(0, 0, 3);
  if (nt > 1){ STAGE(1, 1, 0); STAGE(1, 1, 1); STAGE(1, 1, 2); STAGE(1, 1, 3); }
  if (nt > 1) asm volatile("s_waitcnt vmcnt(8)" ::: "memory");
  else        asm volatile("s_waitcnt vmcnt(0)" ::: "memory");
  BAR;

  for (int t = 0; t < nt; t++){
    const int cur = t & 1;
    const bool pf = (t + 2) < nt;
    RD_A(cur, 0); RD_B(cur, 0);
    BAR; LGKM0;
    __builtin_amdgcn_s_setprio(1); MM(0,0); __builtin_amdgcn_s_setprio(0);
    BAR;
    RD_A(cur, 4);
    BAR; LGKM0;
    __builtin_amdgcn_s_setprio(1); MM(1,0); __builtin_amdgcn_s_setprio(0);
    BAR;
    RD_B(cur, 2);
    if (pf) STAGE(cur, t+2, 0);
    BAR; LGKM0;
    __builtin_amdgcn_s_setprio(1); MM(0,1); __builtin_amdgcn_s_setprio(0);
    BAR;
    if (pf){ STAGE(cur, t+2, 1); STAGE(cur, t+2, 2); STAGE(cur, t+2, 3); }
    BAR;
    __builtin_amdgcn_s_setprio(1); MM(1,1); __builtin_amdgcn_s_setprio(0);
    if (t + 1 < nt){
      if (pf) asm volatile("s_waitcnt vmcnt(8)" ::: "memory");
      else    asm volatile("s_waitcnt vmcnt(0)" ::: "memory");
    }
    BAR;
  }

  #pragma unroll
  for (int m=0;m<8;m++){
    if constexpr (OUTMODE == 2){
      #pragma unroll
      for (int n2=0;n2<2;n2++){
        #pragma unroll
        for (int i=0;i<4;i++){
          int row = bm0 + wr*128 + m*16 + fq*4 + i;
          int col = (bn0>>1) + wc*32 + n2*16 + fr;
          float g = acc[m][n2*2][i], u = acc[m][n2*2+1][i];
          Cb[(size_t)row*ldc + col] = f2bf((g / (1.0f + __expf(-g))) * u);
        }
      }
    } else {
      #pragma unroll
      for (int n=0;n<4;n++){
        #pragma unroll
        for (int i=0;i<4;i++){
          int row = bm0 + wr*128 + m*16 + fq*4 + i;
          int col = bn0 + wc*64 + n*16 + fr;
          size_t idx = (size_t)row*ldc + col;
          if constexpr (OUTMODE == 0) Cf[idx] = acc[m][n][i];
          else                        Cb[idx] = f2bf(acc[m][n][i]);
        }
      }
    }
  }
#undef STAGE
#undef RD_A
#undef RD_B
#undef MM
#undef LGKM0
#undef BAR
}

// distinct symbols per role for unambiguous rocprof attribution
__global__ __launch_bounds__(512) void k_gemm_qkv(const bf16* A, const bf16* B, bf16* Cb, int M, int N, int K, int ldc){
  gemm256_impl<1>(A, B, nullptr, Cb, M, N, K, ldc);
}
__global__ __launch_bounds__(512) void k_gemm_wo(const bf16* A, const bf16* B, bf16* Cb, int M, int N, int K, int ldc){
  gemm256_impl<1>(A, B, nullptr, Cb, M, N, K, ldc);
}
__global__ __launch_bounds__(512) void k_gemm_gu(const bf16* A, const bf16* B, bf16* Cb, int M, int N, int K, int ldc){
  gemm256_impl<2>(A, B, nullptr, Cb, M, N, K, ldc);
}
__global__ __launch_bounds__(512) void k_gemm_down(const bf16* A, const bf16* B, bf16* Cb, int M, int N, int K, int ldc){
  gemm256_impl<1>(A, B, nullptr, Cb, M, N, K, ldc);
}
__global__ __launch_bounds__(512) void k_gemm_out(const bf16* A, const bf16* B, float* Cf, int M, int N, int K, int ldc){
  gemm256_impl<0>(A, B, Cf, nullptr, M, N, K, ldc);
}

// -------- small 128-tile GEMM (embed only: K=64), bf16 out + row remap ------
__global__ __launch_bounds__(256) void k_gemm_embed(const bf16* __restrict__ A,
                                                    const bf16* __restrict__ B0,
                                                    bf16* __restrict__ Cb,
                                                    int M, int N, int K, int ldc){
  constexpr int BM = 128, BN = 128, BK = 32;
  constexpr int WN = BN/2, NR = WN/16, MR = 4;
  __shared__ bf16 lA[BM*BK];
  __shared__ bf16 lB[BN*BK];
  int wid = threadIdx.x >> 6, lane = threadIdx.x & 63;
  int wr = wid >> 1, wc = wid & 1;
  int bm0 = blockIdx.x * BM, bn0 = blockIdx.y * BN;
  int fr = lane & 15, fq = lane >> 4;
  int rowInCh = lane >> 2, colInCh = (lane & 3)*8;
  f32x4 acc[MR][NR] = {};
  const bf16* gA = A + (size_t)bm0*K;
  const bf16* gB = B0 + (size_t)bn0*K;
  for (int k0 = 0; k0 < K; k0 += BK){
    #pragma unroll
    for (int i = 0; i < BM/64; i++){
      int ch = wid + 4*i;
      gload16(gA + (size_t)(16*ch + rowInCh)*K + k0 + colInCh, lA + 16*ch*BK);
    }
    #pragma unroll
    for (int i = 0; i < BN/64; i++){
      int ch = wid + 4*i;
      gload16(gB + (size_t)(16*ch + rowInCh)*K + k0 + colInCh, lB + 16*ch*BK);
    }
    __syncthreads();
    bf16x8 af[MR];
    #pragma unroll
    for (int m=0;m<MR;m++)
      af[m] = *(const bf16x8*)(lA + (wr*64 + m*16 + fr)*BK + fq*8);
    #pragma unroll
    for (int n=0;n<NR;n++){
      bf16x8 bfr = *(const bf16x8*)(lB + (wc*WN + n*16 + fr)*BK + fq*8);
      #pragma unroll
      for (int m=0;m<MR;m++)
        acc[m][n] = __builtin_amdgcn_mfma_f32_16x16x32_bf16(af[m], bfr, acc[m][n], 0,0,0);
    }
    __syncthreads();
  }
  #pragma unroll
  for (int m=0;m<MR;m++)
    #pragma unroll
    for (int n=0;n<NR;n++)
      #pragma unroll
      for (int i=0;i<4;i++){
        int row = bm0 + wr*64 + m*16 + fq*4 + i;
        int col = bn0 + wc*WN + n*16 + fr;
        size_t orow = (size_t)(row + (row>>2) + 1);      // skip special token rows
        Cb[orow*(size_t)ldc + col] = f2bf(acc[m][n][i]);
      }
}

// -------- attention: one wave per (sample, head); QLEN=5, HD=64 -------------
// reads packed qkv [Rc][1280]; writes output into xn rows [Rc][1024]
__global__ __launch_bounds__(256) void k_attn(const bf16* __restrict__ qkv,
                                              bf16* __restrict__ xn,
                                              const float* __restrict__ ctab,
                                              const float* __restrict__ stab){
  int gw   = blockIdx.x*4 + (threadIdx.x>>6);
  int lane = threadIdx.x & 63;
  int sample = gw >> 4, head = gw & 15, kvh = head >> 3;

  float qf[QL], kf[QL], vf[QL];
  #pragma unroll
  for (int t=0;t<QL;t++){
    size_t r = (size_t)(sample*QL + t)*1280;
    qf[t] = bf2f(qkv[r + head*64 + lane]);
    kf[t] = bf2f(qkv[r + 1024 + kvh*64 + lane]);
    vf[t] = bf2f(qkv[r + 1152 + kvh*64 + lane]);
  }
  #pragma unroll
  for (int t=0;t<QL;t++){
    float c = ctab[t*64+lane], s = stab[t*64+lane];
    float qo = __shfl_xor(qf[t], 32);
    float ko = __shfl_xor(kf[t], 32);
    float rq = (lane < 32) ? -qo : qo;
    float rk = (lane < 32) ? -ko : ko;
    qf[t] = qf[t]*c + rq*s;
    kf[t] = kf[t]*c + rk*s;
  }
  float p[QL][QL];
  #pragma unroll
  for (int i=0;i<QL;i++)
    #pragma unroll
    for (int j=0;j<QL;j++) p[i][j] = qf[i]*kf[j];
  #pragma unroll
  for (int off=32; off; off>>=1){
    #pragma unroll
    for (int i=0;i<QL;i++)
      #pragma unroll
      for (int j=0;j<QL;j++) p[i][j] += __shfl_xor(p[i][j], off);
  }
  #pragma unroll
  for (int i=0;i<QL;i++){
    float mx = p[i][0];
    #pragma unroll
    for (int j=1;j<QL;j++) mx = fmaxf(mx, p[i][j]);
    float sum = 0.f;
    #pragma unroll
    for (int j=0;j<QL;j++){ p[i][j] = __expf(p[i][j]-mx); sum += p[i][j]; }
    float rs = 1.0f/sum;
    float o = 0.f;
    #pragma unroll
    for (int j=0;j<QL;j++) o += p[i][j]*vf[j];
    xn[((size_t)(sample*QL+i))*1024 + head*64 + lane] = f2bf(o*rs);
  }
}

__global__ void k_diag(float* out, float v){ out[0] = v; }

extern "C" void kernel_launch(void* const* d_in, const int* in_sizes, int n_in,
                              void* d_out, int out_size, void* d_ws, size_t ws_size,
                              hipStream_t stream){
  const float* audio = (const float*)d_in[0];
  const float* sp    = (const float*)d_in[1];
  const float* inpw  = (const float*)d_in[2];
  const float* ln1   = (const float*)d_in[3];
  const float* wq    = (const float*)d_in[4];
  const float* wk    = (const float*)d_in[5];
  const float* wv    = (const float*)d_in[6];
  const float* wo    = (const float*)d_in[7];
  const float* ln2   = (const float*)d_in[8];
  const float* wg    = (const float*)d_in[9];
  const float* wu    = (const float*)d_in[10];
  const float* wd    = (const float*)d_in[11];
  const float* fnw   = (const float*)d_in[12];
  const float* enc   = (const float*)d_in[13];
  float* out = (float*)d_out;
  char* ws = (char*)d_ws;

  // ---- fixed small-footprint plan: chunk C samples, ONE code path ----------
  // C=2048 -> ~209.5 MiB total; safety shrink C if ws is tighter.
  size_t o_h=0,o_wqkv=0,o_wo=0,o_wgu=0,o_wd=0,o_ct=0,o_st=0,o_xn=0,o_u=0;
  size_t C = 0;
  const size_t tiers[3] = {2048, 1024, 512};
  for (int t=0;t<3;t++){
    size_t c = tiers[t], Rc = c*QL;
    size_t off = 0;
    auto al = [&](size_t b){ size_t o=off; off=(off+b+255)&~(size_t)255; return o; };
    o_h   = al((size_t)MTOK*1024*2);
    o_wqkv= al((size_t)1280*1024*2);
    o_wo  = al((size_t)1024*1024*2);
    o_wgu = al((size_t)8192*1024*2);
    o_wd  = al((size_t)1024*4096*2);
    o_ct  = al(QL*64*4);
    o_st  = al(QL*64*4);
    o_xn  = al(Rc*1024*2);
    size_t ub = Rc*4096*2;                               // act dominates
    if ((size_t)NSAMP*1024*2 > ub) ub = (size_t)NSAMP*1024*2;  // xc (final)
    o_u   = al(ub);
    if (off <= ws_size){ C = c; break; }
  }
  if (C == 0){ k_diag<<<1,1,0,stream>>>(out, (float)ws_size); return; }
  const size_t Rc = C*QL;

  bf16*  h     = (bf16*)(ws + o_h);
  bf16*  wqkvT = (bf16*)(ws + o_wqkv);
  bf16*  woT   = (bf16*)(ws + o_wo);
  bf16*  wguT  = (bf16*)(ws + o_wgu);
  bf16*  wdT   = (bf16*)(ws + o_wd);
  float* ctab  = (float*)(ws + o_ct);
  float* stab  = (float*)(ws + o_st);
  bf16*  xn    = (bf16*)(ws + o_xn);     // chunk: ln-out / attn-out / down-out
  bf16*  ubuf  = (bf16*)(ws + o_u);      // union: qkv / wo-out / act / xc / af16
  bf16*  inprojT = wqkvT;                // alias: pre-loop only
  bf16*  encT    = wguT;                 // alias: post-loop only

  dim3 tb(32,8);
  k_rope_tab<<<1, 320, 0, stream>>>(ctab, stab);
  k_transpose_cvt<<<dim3(32, 2), tb, 0, stream>>>(inpw, inprojT, 64, 1024);
  k_cvt_bf16<<<(32768*64/4)/256, 256, 0, stream>>>(audio, ubuf, 32768*64/4);
  k_fill_special<<<NSAMP*1024/256, 256, 0, stream>>>(sp, h);
  k_gemm_embed<<<dim3(32768/128, 1024/128), 256, 0, stream>>>(
      ubuf, inprojT, h, 32768, 1024, 64, 1024);

  for (int l=0;l<4;l++){
    k_transpose_layer<<<14592, tb, 0, stream>>>(
        wq + (size_t)l*1024*1024, wk + (size_t)l*1024*128, wv + (size_t)l*1024*128,
        wo + (size_t)l*1024*1024, wg + (size_t)l*1024*4096, wu + (size_t)l*1024*4096,
        wd + (size_t)l*4096*1024, wqkvT, woT, wguT, wdT);

    for (size_t c0 = 0; c0 < NSAMP; c0 += C){
      size_t r0 = c0*QL;
      bf16* hc = h + r0*1024;
      k_rmsnorm<<<Rc/4, 256, 0, stream>>>(hc, ln1 + l*1024, xn, (int)Rc, 1024);
      k_gemm_qkv<<<dim3(Rc/256, 5), 512, 0, stream>>>(
          xn, wqkvT, ubuf, (int)Rc, 1280, 1024, 1280);
      k_attn<<<C*16/4, 256, 0, stream>>>(ubuf, xn, ctab, stab);
      k_gemm_wo<<<dim3(Rc/256, 4), 512, 0, stream>>>(
          xn, woT, ubuf, (int)Rc, 1024, 1024, 1024);
      k_addnorm<<<Rc/4, 256, 0, stream>>>(hc, ln2 + l*1024, ubuf, xn, (int)Rc);
      k_gemm_gu<<<dim3(Rc/256, 32), 512, 0, stream>>>(
          xn, wguT, ubuf, (int)Rc, 8192, 1024, 4096);
      k_gemm_down<<<dim3(Rc/256, 4), 512, 0, stream>>>(
          ubuf, wdT, xn, (int)Rc, 1024, 4096, 1024);
      k_add<<<(Rc*1024/8 + 255)/256, 256, 0, stream>>>(hc, xn, (int)(Rc*1024/8));
    }
  }

  k_transpose_cvt<<<dim3(64, 32), tb, 0, stream>>>(enc, encT, 1024, 2048);
  // final: rows n*5 only -> compact xc in ubuf, then output projection
  k_rmsnorm<<<NSAMP/4, 256, 0, stream>>>(h, fnw, ubuf, NSAMP, QL*1024);
  k_gemm_out<<<dim3(NSAMP/256, 2048/256), 512, 0, stream>>>(
      ubuf, encT, out, NSAMP, 2048, 1024, 2048);
}

// Round 9
// 6582.338 us; speedup vs baseline: 1.3488x; 1.0760x over previous
//
#include <hip/hip_runtime.h>
#include <hip/hip_bf16.h>

#define NSAMP 8192
#define QL 5
#define MTOK (NSAMP*QL)   // 40960 tokens

typedef __hip_bfloat16 bf16;
typedef __attribute__((ext_vector_type(8))) __bf16 bf16x8;
typedef __attribute__((ext_vector_type(8))) unsigned short u16x8;
typedef __attribute__((ext_vector_type(4))) float f32x4;

__device__ __forceinline__ float bfu2f(unsigned short u){ return __uint_as_float(((unsigned)u)<<16); }
__device__ __forceinline__ float bf2f(bf16 v){ return __bfloat162float(v); }
__device__ __forceinline__ bf16  f2bf(float v){ return __float2bfloat16(v); }
__device__ __forceinline__ unsigned short f2bfu(float v){
  __hip_bfloat16 b = __float2bfloat16(v);
  return __builtin_bit_cast(unsigned short, b);
}

__device__ __forceinline__ void gload16(const void* g, void* l){
  __builtin_amdgcn_global_load_lds(
      (const __attribute__((address_space(1))) unsigned int*)g,
      (__attribute__((address_space(3))) unsigned int*)l, 16, 0, 0);
}

// -------- generic 32x32 transpose+cvt body ----------------------------------
__device__ __forceinline__ void transpose_body(const float* __restrict__ in,
                                               bf16* __restrict__ out,
                                               int K, int N, int nb, int kb, int rmap){
  __shared__ float tile[32][33];
  int tx = threadIdx.x, ty = threadIdx.y;   // 32 x 8
  #pragma unroll
  for (int j=0;j<4;j++)
    tile[ty+8*j][tx] = in[(size_t)(kb+ty+8*j)*N + nb+tx];
  __syncthreads();
  #pragma unroll
  for (int j=0;j<4;j++){
    int n = nb+ty+8*j;
    int R = (rmap==0) ? n : (((n>>4)<<5) + (n&15) + (rmap==2 ? 16 : 0));
    out[(size_t)R*K + kb+tx] = f2bf(tile[tx][ty+8*j]);
  }
}

__global__ __launch_bounds__(256) void k_transpose_cvt(const float* __restrict__ in,
                                                       bf16* __restrict__ out,
                                                       int K, int N){
  transpose_body(in, out, K, N, blockIdx.x*32, blockIdx.y*32, 0);
}

// all 7 weight matrices of one layer in a single launch (14592 blocks)
__global__ __launch_bounds__(256) void k_transpose_layer(
    const float* __restrict__ wq, const float* __restrict__ wk,
    const float* __restrict__ wv, const float* __restrict__ wo,
    const float* __restrict__ wg, const float* __restrict__ wu,
    const float* __restrict__ wd,
    bf16* __restrict__ wqkvT, bf16* __restrict__ woT,
    bf16* __restrict__ wguT, bf16* __restrict__ wdT){
  int id = blockIdx.x;
  const float* in; bf16* out; int K=1024, N=1024, nbx=32, rmap=0;
  if (id < 1024){ in=wq; out=wqkvT; }
  else if (id < 1152){ id-=1024; in=wk; out=wqkvT+(size_t)1024*1024; N=128; nbx=4; }
  else if (id < 1280){ id-=1152; in=wv; out=wqkvT+(size_t)1152*1024; N=128; nbx=4; }
  else if (id < 2304){ id-=1280; in=wo; out=woT; }
  else if (id < 6400){ id-=2304; in=wg; out=wguT; N=4096; nbx=128; rmap=1; }
  else if (id < 10496){ id-=6400; in=wu; out=wguT; N=4096; nbx=128; rmap=2; }
  else { id-=10496; in=wd; out=wdT; K=4096; N=1024; nbx=32; }
  transpose_body(in, out, K, N, (id % nbx)*32, (id / nbx)*32, rmap);
}

// -------- elementwise fp32 -> bf16 (audio features) -------------------------
__global__ __launch_bounds__(256) void k_cvt_bf16(const float* __restrict__ in,
                                                  bf16* __restrict__ out, int n4){
  int i = blockIdx.x*blockDim.x + threadIdx.x;
  if (i < n4){
    float4 v = ((const float4*)in)[i];
    out[4*i+0]=f2bf(v.x); out[4*i+1]=f2bf(v.y);
    out[4*i+2]=f2bf(v.z); out[4*i+3]=f2bf(v.w);
  }
}

// -------- write special token into h row n*5 (bf16) -------------------------
__global__ __launch_bounds__(256) void k_fill_special(const float* __restrict__ sp,
                                                      bf16* __restrict__ h){
  int i = blockIdx.x*blockDim.x + threadIdx.x;   // NSAMP*1024 threads
  int n = i >> 10, c = i & 1023;
  h[(size_t)n*QL*1024 + c] = f2bf(sp[c]);
}

// -------- RoPE cos/sin tables, scale HD^-0.25 baked in ----------------------
__global__ void k_rope_tab(float* __restrict__ ctab, float* __restrict__ stab){
  int i = threadIdx.x;                 // 320 threads: t=i>>6, d=i&63
  int t = i >> 6, d = i & 63, j = d & 31;
  float invf = __expf(-((float)j/32.0f) * logf(10000.0f));
  float ang  = (float)t * invf;
  const float s = 0.35355339059327373f;   // 64^-0.25
  ctab[i] = cosf(ang)*s;
  stab[i] = sinf(ang)*s;
}

// -------- RMSNorm: bf16 in (stride) -> bf16 out (stride 1024) ---------------
__global__ __launch_bounds__(256) void k_rmsnorm(const bf16* __restrict__ in,
                                                 const float* __restrict__ w,
                                                 bf16* __restrict__ out,
                                                 int nrows, int in_stride){
  int row  = blockIdx.x*4 + (threadIdx.x>>6);
  int lane = threadIdx.x & 63;
  if (row >= nrows) return;
  const bf16* p = in + (size_t)row*in_stride;
  float f[16]; float ss = 0.f;
  #pragma unroll
  for (int i=0;i<2;i++){
    u16x8 v = *(const u16x8*)(p + i*512 + lane*8);
    #pragma unroll
    for (int j=0;j<8;j++){ float x = bfu2f(v[j]); f[i*8+j] = x; ss += x*x; }
  }
  #pragma unroll
  for (int off=32; off; off>>=1) ss += __shfl_xor(ss, off);
  float inv = rsqrtf(ss * (1.0f/1024.0f) + 1e-5f);
  const float4* w4 = (const float4*)w;
  bf16* op = out + (size_t)row*1024;
  #pragma unroll
  for (int i=0;i<2;i++){
    int c = i*512 + lane*8;
    float4 wa = w4[c/4], wb = w4[c/4 + 1];
    u16x8 o;
    o[0]=f2bfu(f[i*8+0]*inv*wa.x); o[1]=f2bfu(f[i*8+1]*inv*wa.y);
    o[2]=f2bfu(f[i*8+2]*inv*wa.z); o[3]=f2bfu(f[i*8+3]*inv*wa.w);
    o[4]=f2bfu(f[i*8+4]*inv*wb.x); o[5]=f2bfu(f[i*8+5]*inv*wb.y);
    o[6]=f2bfu(f[i*8+6]*inv*wb.z); o[7]=f2bfu(f[i*8+7]*inv*wb.w);
    *(u16x8*)(op + c) = o;
  }
}

// -------- fused residual-add + RMSNorm: h += add (write), out = rms(h)*w ----
__global__ __launch_bounds__(256) void k_addnorm(bf16* __restrict__ h,
                                                 const float* __restrict__ w,
                                                 const bf16* __restrict__ add,
                                                 bf16* __restrict__ out,
                                                 int nrows){
  int row  = blockIdx.x*4 + (threadIdx.x>>6);
  int lane = threadIdx.x & 63;
  if (row >= nrows) return;
  bf16* hp = h + (size_t)row*1024;
  const bf16* ap = add + (size_t)row*1024;
  float f[16]; float ss = 0.f;
  u16x8 hv[2], av[2];
  #pragma unroll
  for (int i=0;i<2;i++){
    hv[i] = *(const u16x8*)(hp + i*512 + lane*8);
    av[i] = *(const u16x8*)(ap + i*512 + lane*8);
  }
  #pragma unroll
  for (int i=0;i<2;i++)
    #pragma unroll
    for (int j=0;j<8;j++){
      float x = bfu2f(hv[i][j]) + bfu2f(av[i][j]);
      f[i*8+j] = x; ss += x*x;
    }
  #pragma unroll
  for (int i=0;i<2;i++){
    u16x8 o;
    #pragma unroll
    for (int j=0;j<8;j++) o[j] = f2bfu(f[i*8+j]);
    *(u16x8*)(hp + i*512 + lane*8) = o;
  }
  #pragma unroll
  for (int off=32; off; off>>=1) ss += __shfl_xor(ss, off);
  float inv = rsqrtf(ss * (1.0f/1024.0f) + 1e-5f);
  const float4* w4 = (const float4*)w;
  bf16* op = out + (size_t)row*1024;
  #pragma unroll
  for (int i=0;i<2;i++){
    int c = i*512 + lane*8;
    float4 wa = w4[c/4], wb = w4[c/4 + 1];
    u16x8 o;
    o[0]=f2bfu(f[i*8+0]*inv*wa.x); o[1]=f2bfu(f[i*8+1]*inv*wa.y);
    o[2]=f2bfu(f[i*8+2]*inv*wa.z); o[3]=f2bfu(f[i*8+3]*inv*wa.w);
    o[4]=f2bfu(f[i*8+4]*inv*wb.x); o[5]=f2bfu(f[i*8+5]*inv*wb.y);
    o[6]=f2bfu(f[i*8+6]*inv*wb.z); o[7]=f2bfu(f[i*8+7]*inv*wb.w);
    *(u16x8*)(op + c) = o;
  }
}

// -------- plain residual add: h += d (bf16, fp32 intermediate) --------------
__global__ __launch_bounds__(256) void k_add(bf16* __restrict__ h,
                                             const bf16* __restrict__ d, int n8){
  int i = blockIdx.x*blockDim.x + threadIdx.x;
  if (i < n8){
    u16x8 a = *(const u16x8*)(h + (size_t)i*8);
    u16x8 b = *(const u16x8*)(d + (size_t)i*8);
    u16x8 o;
    #pragma unroll
    for (int j=0;j<8;j++) o[j] = f2bfu(bfu2f(a[j]) + bfu2f(b[j]));
    *(u16x8*)(h + (size_t)i*8) = o;
  }
}

// ======================= 256x256 bf16 MFMA GEMM ==============================
// C[M,N] = A[M,K] @ B^T (B stored [N][K] bf16). 512 threads, 8 waves (2M x 4N).
// BK=64, double-buffered 128KiB LDS, 3-bit XOR swizzle (bank-conflict-free,
// verified round 4: SQ_LDS_BANK_CONFLICT==0). Round-9 schedule: 2 barriers per
// K-tile; all 24 ds_read_b128 issued up front (Q00's 12 order-pinned first),
// counted lgkmcnt(12)/lgkmcnt(0) before Q00/Q10, Q01/Q11 wait-free so LDS reads
// overlap MFMA; staging of t+2 issued after the mid-tile barrier and hides
// under Q01/Q11; counted vmcnt(8) at tile end; setprio around MFMA.
// OUTMODE: 0 fp32 store, 1 bf16 store, 2 silu(g)*u from 16-col-interleaved GU.
template<int OUTMODE>
__device__ __forceinline__ void gemm256_impl(const bf16* __restrict__ A,
                                             const bf16* __restrict__ B,
                                             float* __restrict__ Cf,
                                             bf16* __restrict__ Cb,
                                             int M, int N, int K, int ldc){
  __shared__ bf16 lds[65536];          // 128 KiB: buf p at byte p*65536
  char* ldsb = (char*)lds;
  const int tid  = threadIdx.x;
  const int wid  = tid >> 6, lane = tid & 63;
  const int wr   = wid >> 2, wc  = wid & 3;
  const int fr   = lane & 15, fq = lane >> 4;
  const int swz = (fr & 7) << 4;
  const int cs0 = (fq*16) ^ swz;
  const int cs1 = (fq*16 + 64) ^ swz;
  const int srcR = lane >> 3;
  const int srcC = ((lane & 7) ^ srcR) * 8;

  const int bm0 = blockIdx.x*256, bn0 = blockIdx.y*256;
  const bf16* gA = A + (size_t)bm0*K;
  const bf16* gB = B + (size_t)bn0*K;
  const int nt = K >> 6;

  const int aOff = (wr ? 16384 : 0);
  const int bOff = 32768 + ((wc>>1) ? 16384 : 0) + (wc&1)*8192;
  const char* aB0 = ldsb + aOff + fr*128 + cs0;
  const char* aB1 = ldsb + aOff + fr*128 + cs1;
  const char* bB0 = ldsb + bOff + fr*128 + cs0;
  const char* bB1 = ldsb + bOff + fr*128 + cs1;

  f32x4 acc[8][4] = {};
  bf16x8 aF[8][2], bF[4][2];

#define STAGE(p, t, h) {                                                        \
    const bf16* G_ = ((h) < 2) ? gA : gB;                                       \
    const int rb_ = ((h)&1) ? 128 : 0;                                          \
    const int k0_ = (t) << 6;                                                   \
    _Pragma("unroll")                                                           \
    for (int j_=0;j_<2;j_++){                                                   \
      int blk_ = j_*8 + wid;                                                    \
      gload16(G_ + (size_t)(rb_ + blk_*8 + srcR)*K + k0_ + srcC,               \
              ldsb + (p)*65536 + (h)*16384 + blk_*1024);                        \
    }                                                                           \
  }
#define RD_A(p, m0_) {                                                          \
    _Pragma("unroll")                                                           \
    for (int m_=0;m_<4;m_++)                                                    \
      _Pragma("unroll")                                                         \
      for (int ks_=0;ks_<2;ks_++)                                               \
        aF[(m0_)+m_][ks_] = *(const bf16x8*)((ks_ ? aB1 : aB0) + (p)*65536 + ((m0_)+m_)*2048); \
  }
#define RD_B(p, n0_) {                                                          \
    _Pragma("unroll")                                                           \
    for (int n_=0;n_<2;n_++)                                                    \
      _Pragma("unroll")                                                         \
      for (int ks_=0;ks_<2;ks_++)                                               \
        bF[(n0_)+n_][ks_] = *(const bf16x8*)((ks_ ? bB1 : bB0) + (p)*65536 + ((n0_)+n_)*2048); \
  }
#define MM(qm_, qn_) {                                                          \
    _Pragma("unroll")                                                           \
    for (int m_=0;m_<4;m_++)                                                    \
      _Pragma("unroll")                                                         \
      for (int n_=0;n_<2;n_++)                                                  \
        _Pragma("unroll")                                                       \
        for (int ks_=0;ks_<2;ks_++)                                             \
          acc[(qm_)*4+m_][(qn_)*2+n_] = __builtin_amdgcn_mfma_f32_16x16x32_bf16( \
              aF[(qm_)*4+m_][ks_], bF[(qn_)*2+n_][ks_], acc[(qm_)*4+m_][(qn_)*2+n_], 0,0,0); \
  }
#define SBAR   __builtin_amdgcn_sched_barrier(0)
#define BAR    __builtin_amdgcn_s_barrier()

  STAGE(0, 0, 0); STAGE(0, 0, 1); STAGE(0, 0, 2); STAGE(0, 0, 3);
  if (nt > 1){ STAGE(1, 1, 0); STAGE(1, 1, 1); STAGE(1, 1, 2); STAGE(1, 1, 3); }
  if (nt > 1) asm volatile("s_waitcnt vmcnt(8)" ::: "memory");
  else        asm volatile("s_waitcnt vmcnt(0)" ::: "memory");
  BAR;

  for (int t = 0; t < nt; t++){
    const int cur = t & 1;
    const bool pf = (t + 2) < nt;
    // issue all 24 reads; Q00's 12 (aF0-3, bF0-1) pinned ahead of the rest
    RD_A(cur, 0); RD_B(cur, 0);
    SBAR;
    RD_A(cur, 4); RD_B(cur, 2);
    SBAR;
    // Q00 as soon as its 12 reads land (the other 12 still in flight)
    asm volatile("s_waitcnt lgkmcnt(12)" ::: "memory"); SBAR;
    __builtin_amdgcn_s_setprio(1); MM(0,0); __builtin_amdgcn_s_setprio(0);
    // Q10 after all reads land
    asm volatile("s_waitcnt lgkmcnt(0)" ::: "memory"); SBAR;
    __builtin_amdgcn_s_setprio(1); MM(1,0); __builtin_amdgcn_s_setprio(0);
    BAR;   // all waves past lgkmcnt(0) -> buf[cur] fully read, safe to restage
    if (pf){ STAGE(cur, t+2, 0); STAGE(cur, t+2, 1); STAGE(cur, t+2, 2); STAGE(cur, t+2, 3); }
    // Q01/Q11 wait-free; gload issue hides under MFMA
    __builtin_amdgcn_s_setprio(1); MM(0,1); MM(1,1); __builtin_amdgcn_s_setprio(0);
    if (t + 1 < nt){
      if (pf) asm volatile("s_waitcnt vmcnt(8)" ::: "memory");
      else    asm volatile("s_waitcnt vmcnt(0)" ::: "memory");
    }
    BAR;
  }

  #pragma unroll
  for (int m=0;m<8;m++){
    if constexpr (OUTMODE == 2){
      #pragma unroll
      for (int n2=0;n2<2;n2++){
        #pragma unroll
        for (int i=0;i<4;i++){
          int row = bm0 + wr*128 + m*16 + fq*4 + i;
          int col = (bn0>>1) + wc*32 + n2*16 + fr;
          float g = acc[m][n2*2][i], u = acc[m][n2*2+1][i];
          Cb[(size_t)row*ldc + col] = f2bf((g / (1.0f + __expf(-g))) * u);
        }
      }
    } else {
      #pragma unroll
      for (int n=0;n<4;n++){
        #pragma unroll
        for (int i=0;i<4;i++){
          int row = bm0 + wr*128 + m*16 + fq*4 + i;
          int col = bn0 + wc*64 + n*16 + fr;
          size_t idx = (size_t)row*ldc + col;
          if constexpr (OUTMODE == 0) Cf[idx] = acc[m][n][i];
          else                        Cb[idx] = f2bf(acc[m][n][i]);
        }
      }
    }
  }
#undef STAGE
#undef RD_A
#undef RD_B
#undef MM
#undef SBAR
#undef BAR
}

// distinct symbols per role for unambiguous rocprof attribution
__global__ __launch_bounds__(512) void k_gemm_qkv(const bf16* A, const bf16* B, bf16* Cb, int M, int N, int K, int ldc){
  gemm256_impl<1>(A, B, nullptr, Cb, M, N, K, ldc);
}
__global__ __launch_bounds__(512) void k_gemm_wo(const bf16* A, const bf16* B, bf16* Cb, int M, int N, int K, int ldc){
  gemm256_impl<1>(A, B, nullptr, Cb, M, N, K, ldc);
}
__global__ __launch_bounds__(512) void k_gemm_gu(const bf16* A, const bf16* B, bf16* Cb, int M, int N, int K, int ldc){
  gemm256_impl<2>(A, B, nullptr, Cb, M, N, K, ldc);
}
__global__ __launch_bounds__(512) void k_gemm_down(const bf16* A, const bf16* B, bf16* Cb, int M, int N, int K, int ldc){
  gemm256_impl<1>(A, B, nullptr, Cb, M, N, K, ldc);
}
__global__ __launch_bounds__(512) void k_gemm_out(const bf16* A, const bf16* B, float* Cf, int M, int N, int K, int ldc){
  gemm256_impl<0>(A, B, Cf, nullptr, M, N, K, ldc);
}

// -------- small 128-tile GEMM (embed only: K=64), bf16 out + row remap ------
__global__ __launch_bounds__(256) void k_gemm_embed(const bf16* __restrict__ A,
                                                    const bf16* __restrict__ B0,
                                                    bf16* __restrict__ Cb,
                                                    int M, int N, int K, int ldc){
  constexpr int BM = 128, BN = 128, BK = 32;
  constexpr int WN = BN/2, NR = WN/16, MR = 4;
  __shared__ bf16 lA[BM*BK];
  __shared__ bf16 lB[BN*BK];
  int wid = threadIdx.x >> 6, lane = threadIdx.x & 63;
  int wr = wid >> 1, wc = wid & 1;
  int bm0 = blockIdx.x * BM, bn0 = blockIdx.y * BN;
  int fr = lane & 15, fq = lane >> 4;
  int rowInCh = lane >> 2, colInCh = (lane & 3)*8;
  f32x4 acc[MR][NR] = {};
  const bf16* gA = A + (size_t)bm0*K;
  const bf16* gB = B0 + (size_t)bn0*K;
  for (int k0 = 0; k0 < K; k0 += BK){
    #pragma unroll
    for (int i = 0; i < BM/64; i++){
      int ch = wid + 4*i;
      gload16(gA + (size_t)(16*ch + rowInCh)*K + k0 + colInCh, lA + 16*ch*BK);
    }
    #pragma unroll
    for (int i = 0; i < BN/64; i++){
      int ch = wid + 4*i;
      gload16(gB + (size_t)(16*ch + rowInCh)*K + k0 + colInCh, lB + 16*ch*BK);
    }
    __syncthreads();
    bf16x8 af[MR];
    #pragma unroll
    for (int m=0;m<MR;m++)
      af[m] = *(const bf16x8*)(lA + (wr*64 + m*16 + fr)*BK + fq*8);
    #pragma unroll
    for (int n=0;n<NR;n++){
      bf16x8 bfr = *(const bf16x8*)(lB + (wc*WN + n*16 + fr)*BK + fq*8);
      #pragma unroll
      for (int m=0;m<MR;m++)
        acc[m][n] = __builtin_amdgcn_mfma_f32_16x16x32_bf16(af[m], bfr, acc[m][n], 0,0,0);
    }
    __syncthreads();
  }
  #pragma unroll
  for (int m=0;m<MR;m++)
    #pragma unroll
    for (int n=0;n<NR;n++)
      #pragma unroll
      for (int i=0;i<4;i++){
        int row = bm0 + wr*64 + m*16 + fq*4 + i;
        int col = bn0 + wc*WN + n*16 + fr;
        size_t orow = (size_t)(row + (row>>2) + 1);      // skip special token rows
        Cb[orow*(size_t)ldc + col] = f2bf(acc[m][n][i]);
      }
}

// -------- attention: one wave per (sample, head); QLEN=5, HD=64 -------------
// reads packed qkv [Rc][1280]; writes output into xn rows [Rc][1024]
__global__ __launch_bounds__(256) void k_attn(const bf16* __restrict__ qkv,
                                              bf16* __restrict__ xn,
                                              const float* __restrict__ ctab,
                                              const float* __restrict__ stab){
  int gw   = blockIdx.x*4 + (threadIdx.x>>6);
  int lane = threadIdx.x & 63;
  int sample = gw >> 4, head = gw & 15, kvh = head >> 3;

  float qf[QL], kf[QL], vf[QL];
  #pragma unroll
  for (int t=0;t<QL;t++){
    size_t r = (size_t)(sample*QL + t)*1280;
    qf[t] = bf2f(qkv[r + head*64 + lane]);
    kf[t] = bf2f(qkv[r + 1024 + kvh*64 + lane]);
    vf[t] = bf2f(qkv[r + 1152 + kvh*64 + lane]);
  }
  #pragma unroll
  for (int t=0;t<QL;t++){
    float c = ctab[t*64+lane], s = stab[t*64+lane];
    float qo = __shfl_xor(qf[t], 32);
    float ko = __shfl_xor(kf[t], 32);
    float rq = (lane < 32) ? -qo : qo;
    float rk = (lane < 32) ? -ko : ko;
    qf[t] = qf[t]*c + rq*s;
    kf[t] = kf[t]*c + rk*s;
  }
  float p[QL][QL];
  #pragma unroll
  for (int i=0;i<QL;i++)
    #pragma unroll
    for (int j=0;j<QL;j++) p[i][j] = qf[i]*kf[j];
  #pragma unroll
  for (int off=32; off; off>>=1){
    #pragma unroll
    for (int i=0;i<QL;i++)
      #pragma unroll
      for (int j=0;j<QL;j++) p[i][j] += __shfl_xor(p[i][j], off);
  }
  #pragma unroll
  for (int i=0;i<QL;i++){
    float mx = p[i][0];
    #pragma unroll
    for (int j=1;j<QL;j++) mx = fmaxf(mx, p[i][j]);
    float sum = 0.f;
    #pragma unroll
    for (int j=0;j<QL;j++){ p[i][j] = __expf(p[i][j]-mx); sum += p[i][j]; }
    float rs = 1.0f/sum;
    float o = 0.f;
    #pragma unroll
    for (int j=0;j<QL;j++) o += p[i][j]*vf[j];
    xn[((size_t)(sample*QL+i))*1024 + head*64 + lane] = f2bf(o*rs);
  }
}

__global__ void k_diag(float* out, float v){ out[0] = v; }

extern "C" void kernel_launch(void* const* d_in, const int* in_sizes, int n_in,
                              void* d_out, int out_size, void* d_ws, size_t ws_size,
                              hipStream_t stream){
  const float* audio = (const float*)d_in[0];
  const float* sp    = (const float*)d_in[1];
  const float* inpw  = (const float*)d_in[2];
  const float* ln1   = (const float*)d_in[3];
  const float* wq    = (const float*)d_in[4];
  const float* wk    = (const float*)d_in[5];
  const float* wv    = (const float*)d_in[6];
  const float* wo    = (const float*)d_in[7];
  const float* ln2   = (const float*)d_in[8];
  const float* wg    = (const float*)d_in[9];
  const float* wu    = (const float*)d_in[10];
  const float* wd    = (const float*)d_in[11];
  const float* fnw   = (const float*)d_in[12];
  const float* enc   = (const float*)d_in[13];
  float* out = (float*)d_out;
  char* ws = (char*)d_ws;

  // ---- fixed small-footprint plan: chunk C samples, ONE code path ----------
  // C=2048 -> ~209.5 MiB total; safety shrink C if ws is tighter.
  size_t o_h=0,o_wqkv=0,o_wo=0,o_wgu=0,o_wd=0,o_ct=0,o_st=0,o_xn=0,o_u=0;
  size_t C = 0;
  const size_t tiers[3] = {2048, 1024, 512};
  for (int t=0;t<3;t++){
    size_t c = tiers[t], Rc = c*QL;
    size_t off = 0;
    auto al = [&](size_t b){ size_t o=off; off=(off+b+255)&~(size_t)255; return o; };
    o_h   = al((size_t)MTOK*1024*2);
    o_wqkv= al((size_t)1280*1024*2);
    o_wo  = al((size_t)1024*1024*2);
    o_wgu = al((size_t)8192*1024*2);
    o_wd  = al((size_t)1024*4096*2);
    o_ct  = al(QL*64*4);
    o_st  = al(QL*64*4);
    o_xn  = al(Rc*1024*2);
    size_t ub = Rc*4096*2;                               // act dominates
    if ((size_t)NSAMP*1024*2 > ub) ub = (size_t)NSAMP*1024*2;  // xc (final)
    o_u   = al(ub);
    if (off <= ws_size){ C = c; break; }
  }
  if (C == 0){ k_diag<<<1,1,0,stream>>>(out, (float)ws_size); return; }
  const size_t Rc = C*QL;

  bf16*  h     = (bf16*)(ws + o_h);
  bf16*  wqkvT = (bf16*)(ws + o_wqkv);
  bf16*  woT   = (bf16*)(ws + o_wo);
  bf16*  wguT  = (bf16*)(ws + o_wgu);
  bf16*  wdT   = (bf16*)(ws + o_wd);
  float* ctab  = (float*)(ws + o_ct);
  float* stab  = (float*)(ws + o_st);
  bf16*  xn    = (bf16*)(ws + o_xn);     // chunk: ln-out / attn-out / down-out
  bf16*  ubuf  = (bf16*)(ws + o_u);      // union: qkv / wo-out / act / xc / af16
  bf16*  inprojT = wqkvT;                // alias: pre-loop only
  bf16*  encT    = wguT;                 // alias: post-loop only

  dim3 tb(32,8);
  k_rope_tab<<<1, 320, 0, stream>>>(ctab, stab);
  k_transpose_cvt<<<dim3(32, 2), tb, 0, stream>>>(inpw, inprojT, 64, 1024);
  k_cvt_bf16<<<(32768*64/4)/256, 256, 0, stream>>>(audio, ubuf, 32768*64/4);
  k_fill_special<<<NSAMP*1024/256, 256, 0, stream>>>(sp, h);
  k_gemm_embed<<<dim3(32768/128, 1024/128), 256, 0, stream>>>(
      ubuf, inprojT, h, 32768, 1024, 64, 1024);

  for (int l=0;l<4;l++){
    k_transpose_layer<<<14592, tb, 0, stream>>>(
        wq + (size_t)l*1024*1024, wk + (size_t)l*1024*128, wv + (size_t)l*1024*128,
        wo + (size_t)l*1024*1024, wg + (size_t)l*1024*4096, wu + (size_t)l*1024*4096,
        wd + (size_t)l*4096*1024, wqkvT, woT, wguT, wdT);

    for (size_t c0 = 0; c0 < NSAMP; c0 += C){
      size_t r0 = c0*QL;
      bf16* hc = h + r0*1024;
      k_rmsnorm<<<Rc/4, 256, 0, stream>>>(hc, ln1 + l*1024, xn, (int)Rc, 1024);
      k_gemm_qkv<<<dim3(Rc/256, 5), 512, 0, stream>>>(
          xn, wqkvT, ubuf, (int)Rc, 1280, 1024, 1280);
      k_attn<<<C*16/4, 256, 0, stream>>>(ubuf, xn, ctab, stab);
      k_gemm_wo<<<dim3(Rc/256, 4), 512, 0, stream>>>(
          xn, woT, ubuf, (int)Rc, 1024, 1024, 1024);
      k_addnorm<<<Rc/4, 256, 0, stream>>>(hc, ln2 + l*1024, ubuf, xn, (int)Rc);
      k_gemm_gu<<<dim3(Rc/256, 32), 512, 0, stream>>>(
          xn, wguT, ubuf, (int)Rc, 8192, 1024, 4096);
      k_gemm_down<<<dim3(Rc/256, 4), 512, 0, stream>>>(
          ubuf, wdT, xn, (int)Rc, 1024, 4096, 1024);
      k_add<<<(Rc*1024/8 + 255)/256, 256, 0, stream>>>(hc, xn, (int)(Rc*1024/8));
    }
  }

  k_transpose_cvt<<<dim3(64, 32), tb, 0, stream>>>(enc, encT, 1024, 2048);
  // final: rows n*5 only -> compact xc in ubuf, then output projection
  k_rmsnorm<<<NSAMP/4, 256, 0, stream>>>(h, fnw, ubuf, NSAMP, QL*1024);
  k_gemm_out<<<dim3(NSAMP/256, 2048/256), 512, 0, stream>>>(
      ubuf, encT, out, NSAMP, 2048, 1024, 2048);
}